// Round 6
// baseline (1320.522 us; speedup 1.0000x reference)
//
#include <hip/hip_runtime.h>
#include <hip/hip_bf16.h>
#include <stdint.h>

#define EPSV 1e-5f

typedef __bf16 bf16x8 __attribute__((ext_vector_type(8)));
typedef float f32x4 __attribute__((ext_vector_type(4)));

// ---------------------------------------------------------------------------
// round-to-nearest bf16 split: f = hi + lo (both bf16), |f-(hi+lo)| ~ 2^-18 |f|
// ---------------------------------------------------------------------------
__device__ __forceinline__ void bf16split(float f, ushort& h, ushort& l) {
    union { float f; uint32_t u; } a; a.f = f;
    uint32_t r = a.u + 0x7FFFu + ((a.u >> 16) & 1u);
    h = (ushort)(r >> 16);
    union { uint32_t u; float f; } hf; hf.u = ((uint32_t)h) << 16;
    float lof = f - hf.f;
    union { float f; uint32_t u; } b; b.f = lof;
    uint32_t r2 = b.u + 0x7FFFu + ((b.u >> 16) & 1u);
    l = (ushort)(r2 >> 16);
}

__device__ __forceinline__ void gload_lds16(const void* g, void* l) {
    __builtin_amdgcn_global_load_lds(
        (const __attribute__((address_space(1))) uint32_t*)g,
        (__attribute__((address_space(3))) uint32_t*)l, 16, 0, 0);
}

// ---------------------------------------------------------------------------
// Block reduction helpers (256 threads = 4 waves of 64)
// ---------------------------------------------------------------------------
__device__ __forceinline__ float block_sum256(float v, float* red) {
#pragma unroll
    for (int off = 32; off; off >>= 1) v += __shfl_down(v, off);
    int lane = threadIdx.x & 63, w = threadIdx.x >> 6;
    __syncthreads();
    if (lane == 0) red[w] = v;
    __syncthreads();
    return red[0] + red[1] + red[2] + red[3];
}

// ---------------------------------------------------------------------------
// Row LayerNorm -> packed hi/lo bf16 output.
// Packed layout: Ap[row][kt][half][km]  (ushort), kt = k/32, km = k%32,
// half 0 = hi, 1 = lo. Row stride = D*2 ushorts = D*4 bytes.
// ---------------------------------------------------------------------------
__global__ __launch_bounds__(256)
void ln_pack(const float* __restrict__ X, const float* __restrict__ g,
             const float* __restrict__ b, ushort* __restrict__ Ap, int D) {
    __shared__ float red[4];
    int row = blockIdx.x;
    const float* x = X + (size_t)row * D;
    ushort* ap = Ap + (size_t)row * (D * 2);
    int tid = threadIdx.x;
    int nvec = D >> 2;

    float s = 0.f, sq = 0.f;
    for (int i = tid; i < nvec; i += 256) {
        float4 v = ((const float4*)x)[i];
        s += v.x + v.y + v.z + v.w;
        sq += v.x * v.x + v.y * v.y + v.z * v.z + v.w * v.w;
    }
    float ts = block_sum256(s, red);
    float tq = block_sum256(sq, red);
    float invD = 1.f / (float)D;
    float mu = ts * invD;
    float var = tq * invD - mu * mu;
    float rstd = rsqrtf(var + EPSV);

    for (int i = tid; i < nvec; i += 256) {
        float4 v = ((const float4*)x)[i];
        float4 gv = ((const float4*)g)[i];
        float4 bv = ((const float4*)b)[i];
        float o[4];
        o[0] = (v.x - mu) * rstd * gv.x + bv.x;
        o[1] = (v.y - mu) * rstd * gv.y + bv.y;
        o[2] = (v.z - mu) * rstd * gv.z + bv.z;
        o[3] = (v.w - mu) * rstd * gv.w + bv.w;
        ushort hi[4], lo[4];
#pragma unroll
        for (int j = 0; j < 4; ++j) bf16split(o[j], hi[j], lo[j]);
        int kt = i >> 3;           // (4i)/32
        int km = (i & 7) << 2;     // (4i)%32
        ushort* dst = ap + kt * 64 + km;
        *(ushort4*)dst = *(ushort4*)hi;
        *(ushort4*)(dst + 32) = *(ushort4*)lo;
    }
}

// ---------------------------------------------------------------------------
// Weight convert+transpose: W[K][N] fp32 -> Wp[n][kt][half][km] packed bf16.
// grid = (ceil(N/64), K/32), block = 64.
// ---------------------------------------------------------------------------
__global__ __launch_bounds__(64)
void conv_w(const float* __restrict__ W, ushort* __restrict__ Wp, int K, int N) {
    int n = blockIdx.x * 64 + threadIdx.x;
    int kt = blockIdx.y;
    if (n >= N) return;
    ushort hi[32], lo[32];
#pragma unroll
    for (int j = 0; j < 32; ++j) {
        float f = W[(size_t)(kt * 32 + j) * N + n];
        bf16split(f, hi[j], lo[j]);
    }
    ushort* dst = Wp + (size_t)n * (K * 2) + kt * 64;
    uint4* d = (uint4*)dst;
    const uint4* ph = (const uint4*)hi;
    const uint4* pl = (const uint4*)lo;
    d[0] = ph[0]; d[1] = ph[1]; d[2] = ph[2]; d[3] = ph[3];
    d[4] = pl[0]; d[5] = pl[1]; d[6] = pl[2]; d[7] = pl[3];
}

// ---------------------------------------------------------------------------
// 256x256-tile split-bf16 MFMA GEMM, 8 waves, double-buffered LDS,
// issue-early staging, ONE barrier per K-tile; T5 setprio around MFMA.
// ---------------------------------------------------------------------------
template <int MODE>
__global__ __launch_bounds__(512, 2)
void gemm_mfma256(const ushort* __restrict__ Ap, const ushort* __restrict__ Bp,
                  const float* __restrict__ bias, float* __restrict__ C,
                  int M, int N, int K) {
    __shared__ ushort Abuf[2][256 * 64];   // 2 x 32 KB
    __shared__ ushort Bbuf[2][256 * 64];   // 2 x 32 KB

    const int tid = threadIdx.x;
    const int lane = tid & 63;
    const int wv = tid >> 6;       // 0..7
    const int wr = wv >> 2;        // 0..1  (M)
    const int wc = wv & 3;         // 0..3  (N)

    // T1 XCD-chunked swizzle
    int lid = blockIdx.y * gridDim.x + blockIdx.x;
    int nwg = gridDim.x * gridDim.y;
    int chunk = nwg >> 3;
    int swz = (lid & 7) * chunk + (lid >> 3);
    int nIdx = swz % gridDim.y;
    int mIdx = swz / gridDim.y;
    const int m0 = mIdx * 256, n0 = nIdx * 256;

    const int nt = K >> 5;
    const size_t rowB = (size_t)K * 4;   // packed row bytes

    int srow[4], sq[4];
#pragma unroll
    for (int i = 0; i < 4; ++i) {
        int s = i * 512 + tid;
        srow[i] = s >> 3;                  // 0..255
        sq[i] = (s & 7) ^ (srow[i] & 7);
    }

    f32x4 acc[8][4] = {};

    // prologue: stage tile 0 into buffer 0
#pragma unroll
    for (int i = 0; i < 4; ++i) {
        const char* sA = (const char*)Ap + (size_t)(m0 + srow[i]) * rowB + sq[i] * 16;
        const char* sB = (const char*)Bp + (size_t)(n0 + srow[i]) * rowB + sq[i] * 16;
        gload_lds16(sA, (char*)Abuf[0] + (i * 512 + tid) * 16);
        gload_lds16(sB, (char*)Bbuf[0] + (i * 512 + tid) * 16);
    }
    __syncthreads();

    int p = 0;
    for (int kt = 0; kt < nt; ++kt) {
        if (kt + 1 < nt) {
            const size_t koff = (size_t)(kt + 1) * 128;
#pragma unroll
            for (int i = 0; i < 4; ++i) {
                const char* sA = (const char*)Ap + (size_t)(m0 + srow[i]) * rowB + koff + sq[i] * 16;
                const char* sB = (const char*)Bp + (size_t)(n0 + srow[i]) * rowB + koff + sq[i] * 16;
                gload_lds16(sA, (char*)Abuf[p ^ 1] + (i * 512 + tid) * 16);
                gload_lds16(sB, (char*)Bbuf[p ^ 1] + (i * 512 + tid) * 16);
            }
        }

        const char* Ab = (const char*)Abuf[p];
        const char* Bb = (const char*)Bbuf[p];
        const int g = lane >> 4;
        const int rr = lane & 15;

        // P1: hi(A) x hi(B)
        bf16x8 ah[8], bh[4];
#pragma unroll
        for (int m = 0; m < 8; ++m) {
            int rA = wr * 128 + m * 16 + rr;
            ah[m] = *(const bf16x8*)(Ab + rA * 128 + ((g ^ (rA & 7)) * 16));
        }
#pragma unroll
        for (int n = 0; n < 4; ++n) {
            int rB = wc * 64 + n * 16 + rr;
            bh[n] = *(const bf16x8*)(Bb + rB * 128 + ((g ^ (rB & 7)) * 16));
        }
        __builtin_amdgcn_s_setprio(1);
#pragma unroll
        for (int m = 0; m < 8; ++m)
#pragma unroll
            for (int n = 0; n < 4; ++n)
                acc[m][n] = __builtin_amdgcn_mfma_f32_16x16x32_bf16(ah[m], bh[n], acc[m][n], 0, 0, 0);
        __builtin_amdgcn_s_setprio(0);

        // P2: lo(A) x hi(B)
        {
            bf16x8 al[8];
#pragma unroll
            for (int m = 0; m < 8; ++m) {
                int rA = wr * 128 + m * 16 + rr;
                al[m] = *(const bf16x8*)(Ab + rA * 128 + (((g + 4) ^ (rA & 7)) * 16));
            }
            __builtin_amdgcn_s_setprio(1);
#pragma unroll
            for (int m = 0; m < 8; ++m)
#pragma unroll
                for (int n = 0; n < 4; ++n)
                    acc[m][n] = __builtin_amdgcn_mfma_f32_16x16x32_bf16(al[m], bh[n], acc[m][n], 0, 0, 0);
            __builtin_amdgcn_s_setprio(0);
        }
        // P3: hi(A) x lo(B)
        {
            bf16x8 bl[4];
#pragma unroll
            for (int n = 0; n < 4; ++n) {
                int rB = wc * 64 + n * 16 + rr;
                bl[n] = *(const bf16x8*)(Bb + rB * 128 + (((g + 4) ^ (rB & 7)) * 16));
            }
            __builtin_amdgcn_s_setprio(1);
#pragma unroll
            for (int m = 0; m < 8; ++m)
#pragma unroll
                for (int n = 0; n < 4; ++n)
                    acc[m][n] = __builtin_amdgcn_mfma_f32_16x16x32_bf16(ah[m], bl[n], acc[m][n], 0, 0, 0);
            __builtin_amdgcn_s_setprio(0);
        }

        __syncthreads();
        p ^= 1;
    }

    // epilogue: C/D layout col = lane&15, row = (lane>>4)*4 + j  [m89/m91]
#pragma unroll
    for (int m = 0; m < 8; ++m) {
        int r = m0 + wr * 128 + m * 16 + (lane >> 4) * 4;
#pragma unroll
        for (int n = 0; n < 4; ++n) {
            int c = n0 + wc * 64 + n * 16 + (lane & 15);
            float bv = bias[c];
#pragma unroll
            for (int j = 0; j < 4; ++j) {
                float v = acc[m][n][j] + bv;
                float* cp = &C[(size_t)(r + j) * N + c];
                if (MODE == 0) *cp = fmaxf(v, 0.f);
                else if (MODE == 1) *cp = *cp + fmaxf(v, 0.f);
                else *cp = v;
            }
        }
    }
}

// ---------------------------------------------------------------------------
// 128x128-tile split-bf16 MFMA GEMM (proven) -- head (N=128).
// ---------------------------------------------------------------------------
template <int MODE>
__global__ __launch_bounds__(256)
void gemm_mfma(const ushort* __restrict__ Ap, const ushort* __restrict__ Bp,
               const float* __restrict__ bias, float* __restrict__ C,
               int M, int N, int K) {
    __shared__ ushort Ash[128 * 64];
    __shared__ ushort Bsh[128 * 64];

    const int tid = threadIdx.x;
    const int lane = tid & 63;
    const int wv = tid >> 6;
    const int wr = wv >> 1, wc = wv & 1;

    int lid = blockIdx.y * gridDim.x + blockIdx.x;
    int nwg = gridDim.x * gridDim.y;
    int chunk = nwg >> 3;
    int swz = (lid & 7) * chunk + (lid >> 3);
    int nIdx = swz % gridDim.y;
    int mIdx = swz / gridDim.y;
    const int m0 = mIdx * 128, n0 = nIdx * 128;

    const int ktc = K >> 5;
    const size_t rowB = (size_t)K * 4;

    int srow[4], sq[4];
#pragma unroll
    for (int i = 0; i < 4; ++i) {
        int s = i * 256 + tid;
        srow[i] = s >> 3;
        sq[i] = (s & 7) ^ (srow[i] & 7);
    }

    f32x4 acc[4][4] = {};

    for (int kt = 0; kt < ktc; ++kt) {
        __syncthreads();
#pragma unroll
        for (int i = 0; i < 4; ++i) {
            const char* sA = (const char*)Ap + (size_t)(m0 + srow[i]) * rowB + kt * 128 + sq[i] * 16;
            const char* sB = (const char*)Bp + (size_t)(n0 + srow[i]) * rowB + kt * 128 + sq[i] * 16;
            gload_lds16(sA, (char*)Ash + (i * 256 + tid) * 16);
            gload_lds16(sB, (char*)Bsh + (i * 256 + tid) * 16);
        }
        __syncthreads();

        bf16x8 ah[4], al[4], bh[4], bl[4];
        const int g = lane >> 4;
        const int rr = lane & 15;
#pragma unroll
        for (int t = 0; t < 4; ++t) {
            int rA = wr * 64 + t * 16 + rr;
            const char* baseA = (const char*)Ash + rA * 128;
            ah[t] = *(const bf16x8*)(baseA + ((g ^ (rA & 7)) * 16));
            al[t] = *(const bf16x8*)(baseA + (((g + 4) ^ (rA & 7)) * 16));
            int rBr = wc * 64 + t * 16 + rr;
            const char* baseB = (const char*)Bsh + rBr * 128;
            bh[t] = *(const bf16x8*)(baseB + ((g ^ (rBr & 7)) * 16));
            bl[t] = *(const bf16x8*)(baseB + (((g + 4) ^ (rBr & 7)) * 16));
        }
#pragma unroll
        for (int mi = 0; mi < 4; ++mi)
#pragma unroll
            for (int ni = 0; ni < 4; ++ni) {
                acc[mi][ni] = __builtin_amdgcn_mfma_f32_16x16x32_bf16(ah[mi], bh[ni], acc[mi][ni], 0, 0, 0);
                acc[mi][ni] = __builtin_amdgcn_mfma_f32_16x16x32_bf16(al[mi], bh[ni], acc[mi][ni], 0, 0, 0);
                acc[mi][ni] = __builtin_amdgcn_mfma_f32_16x16x32_bf16(ah[mi], bl[ni], acc[mi][ni], 0, 0, 0);
            }
    }

#pragma unroll
    for (int mi = 0; mi < 4; ++mi) {
        int r = m0 + wr * 64 + mi * 16 + (lane >> 4) * 4;
#pragma unroll
        for (int ni = 0; ni < 4; ++ni) {
            int c = n0 + wc * 64 + ni * 16 + (lane & 15);
            float bv = bias[c];
#pragma unroll
            for (int j = 0; j < 4; ++j) {
                float v = acc[mi][ni][j] + bv;
                float* cp = &C[(size_t)(r + j) * N + c];
                if (MODE == 0) *cp = fmaxf(v, 0.f);
                else if (MODE == 1) *cp = *cp + fmaxf(v, 0.f);
                else *cp = v;
            }
        }
    }
}

// ---------------------------------------------------------------------------
// 16-wide simultaneous block reduction: v[16] per thread -> out[16] (shared).
// ---------------------------------------------------------------------------
template <bool MAXOP>
__device__ __forceinline__ void red16(const float* v, float* out, float (*scr)[4]) {
    int lane = threadIdx.x & 63, wv = threadIdx.x >> 6, tid = threadIdx.x;
#pragma unroll
    for (int oo = 0; oo < 16; ++oo) {
        float r = v[oo];
#pragma unroll
        for (int m = 1; m < 64; m <<= 1) {
            float t = __shfl_xor(r, m);
            r = MAXOP ? fmaxf(r, t) : r + t;
        }
        if (lane == 0) scr[oo][wv] = r;
    }
    __syncthreads();
    if (tid < 16) {
        float a = scr[tid][0], b = scr[tid][1], c = scr[tid][2], d = scr[tid][3];
        out[tid] = MAXOP ? fmaxf(fmaxf(a, b), fmaxf(c, d)) : (a + b + c + d);
    }
    __syncthreads();
}

// ---------------------------------------------------------------------------
// Attention over time, 16 outputs per block. grid = 64 bs * 8 ogroups.
// GEMV phases: thread (jgrp = tid>>2, kp = tid&3) owns 4 output columns
// j = jgrp*4+{0..3}, iterating k = 4*i+kp (k-partition). Partials reduced
// over kp with 2x shfl_xor; thread keeps column jj==kp so j == tid, which
// keeps all LN/softmax phases in the proven tid-mapped layout.
// buf rows padded to 20 floats so the 4 kp lanes hit disjoint bank quads.
// ---------------------------------------------------------------------------
__global__ __launch_bounds__(256)
void attn_g16(const float* __restrict__ fc,
              const float* __restrict__ g1, const float* __restrict__ b1,
              const float* __restrict__ Wa1, const float* __restrict__ ba1,
              const float* __restrict__ g2, const float* __restrict__ b2,
              const float* __restrict__ Wa2, const float* __restrict__ ba2,
              float* __restrict__ out) {
    __shared__ float buf[257][20];
    __shared__ float scr[16][4];
    __shared__ float sS[16], sQ[16], sO[16];

    int bs = blockIdx.x >> 3;
    int o0 = (blockIdx.x & 7) * 16;
    int tid = threadIdx.x;
    int jgrp = tid >> 2;
    int kp = tid & 3;

    float vv[16], tmp[16];
    const float4* fp = (const float4*)(fc + (size_t)(bs * 256 + tid) * 128 + o0);
#pragma unroll
    for (int q = 0; q < 4; ++q) {
        float4 t = fp[q];
        vv[4 * q] = t.x; vv[4 * q + 1] = t.y; vv[4 * q + 2] = t.z; vv[4 * q + 3] = t.w;
    }

#pragma unroll
    for (int oo = 0; oo < 16; ++oo) tmp[oo] = vv[oo] * vv[oo];
    red16<false>(vv, sS, scr);
    red16<false>(tmp, sQ, scr);

    // LN over 257-vector [v_0..255, mean]; buf[l][oo] = normalized t
    float gl = g1[tid], bl = b1[tid];
#pragma unroll
    for (int oo = 0; oo < 16; ++oo) {
        float s = sS[oo], q = sQ[oo];
        float mean = s * (1.f / 256.f);
        float mu = (s + mean) * (1.f / 257.f);
        float var = (q + mean * mean) * (1.f / 257.f) - mu * mu;
        float rstd = rsqrtf(var + EPSV);
        tmp[oo] = (vv[oo] - mu) * rstd * gl + bl;
    }
#pragma unroll
    for (int q = 0; q < 4; ++q)
        *(float4*)&buf[tid][4 * q] = *(float4*)&tmp[4 * q];
    if (tid < 16) {
        int oo = tid;
        float s = sS[oo], q = sQ[oo];
        float mean = s * (1.f / 256.f);
        float mu = (s + mean) * (1.f / 257.f);
        float var = (q + mean * mean) * (1.f / 257.f) - mu * mu;
        float rstd = rsqrtf(var + EPSV);
        buf[256][oo] = (mean - mu) * rstd * g1[256] + b1[256];
    }
    __syncthreads();

    // GEMV1: acc1[oo][jj] = sum_{k in kp's set} buf[k][oo] * Wa1[k][jgrp*4+jj]
    float acc1[16][4] = {};
#pragma unroll 2
    for (int i = 0; i < 64; ++i) {
        int k = 4 * i + kp;
        float4 w4 = *(const float4*)&Wa1[(size_t)k * 256 + jgrp * 4];
        float4 t0 = *(const float4*)&buf[k][0];
        float4 t1 = *(const float4*)&buf[k][4];
        float4 t2 = *(const float4*)&buf[k][8];
        float4 t3 = *(const float4*)&buf[k][12];
        float bv[16] = { t0.x, t0.y, t0.z, t0.w, t1.x, t1.y, t1.z, t1.w,
                         t2.x, t2.y, t2.z, t2.w, t3.x, t3.y, t3.z, t3.w };
#pragma unroll
        for (int oo = 0; oo < 16; ++oo) {
            acc1[oo][0] = fmaf(bv[oo], w4.x, acc1[oo][0]);
            acc1[oo][1] = fmaf(bv[oo], w4.y, acc1[oo][1]);
            acc1[oo][2] = fmaf(bv[oo], w4.z, acc1[oo][2]);
            acc1[oo][3] = fmaf(bv[oo], w4.w, acc1[oo][3]);
        }
    }
    if (kp == 0) {   // k = 256 tail
        float4 w4 = *(const float4*)&Wa1[(size_t)256 * 256 + jgrp * 4];
#pragma unroll
        for (int oo = 0; oo < 16; ++oo) {
            float bv = buf[256][oo];
            acc1[oo][0] = fmaf(bv, w4.x, acc1[oo][0]);
            acc1[oo][1] = fmaf(bv, w4.y, acc1[oo][1]);
            acc1[oo][2] = fmaf(bv, w4.z, acc1[oo][2]);
            acc1[oo][3] = fmaf(bv, w4.w, acc1[oo][3]);
        }
    }
    // reduce partials over kp (lanes tid^1, tid^2 share jgrp)
    float a_[16];
#pragma unroll
    for (int oo = 0; oo < 16; ++oo) {
#pragma unroll
        for (int jj = 0; jj < 4; ++jj) {
            acc1[oo][jj] += __shfl_xor(acc1[oo][jj], 1);
            acc1[oo][jj] += __shfl_xor(acc1[oo][jj], 2);
        }
        float v01 = (kp & 1) ? acc1[oo][1] : acc1[oo][0];
        float v23 = (kp & 1) ? acc1[oo][3] : acc1[oo][2];
        a_[oo] = (kp & 2) ? v23 : v01;   // j == tid
    }
    float bb = ba1[tid];
#pragma unroll
    for (int oo = 0; oo < 16; ++oo) a_[oo] = fmaxf(a_[oo] + bb, 0.f);

    // LN over a (256 j's)
#pragma unroll
    for (int oo = 0; oo < 16; ++oo) tmp[oo] = a_[oo] * a_[oo];
    red16<false>(a_, sS, scr);
    red16<false>(tmp, sQ, scr);

    float g2l = g2[tid], b2l = b2[tid];
#pragma unroll
    for (int oo = 0; oo < 16; ++oo) {
        float mu2 = sS[oo] * (1.f / 256.f);
        float rstd2 = rsqrtf(sQ[oo] * (1.f / 256.f) - mu2 * mu2 + EPSV);
        tmp[oo] = (a_[oo] - mu2) * rstd2 * g2l + b2l;
    }
#pragma unroll
    for (int q = 0; q < 4; ++q)
        *(float4*)&buf[tid][4 * q] = *(float4*)&tmp[4 * q];
    __syncthreads();

    // GEMV2: same decomposition over j (256), l == tid
    float acc2[16][4] = {};
#pragma unroll 2
    for (int i = 0; i < 64; ++i) {
        int k = 4 * i + kp;
        float4 w4 = *(const float4*)&Wa2[(size_t)k * 256 + jgrp * 4];
        float4 t0 = *(const float4*)&buf[k][0];
        float4 t1 = *(const float4*)&buf[k][4];
        float4 t2 = *(const float4*)&buf[k][8];
        float4 t3 = *(const float4*)&buf[k][12];
        float bv[16] = { t0.x, t0.y, t0.z, t0.w, t1.x, t1.y, t1.z, t1.w,
                         t2.x, t2.y, t2.z, t2.w, t3.x, t3.y, t3.z, t3.w };
#pragma unroll
        for (int oo = 0; oo < 16; ++oo) {
            acc2[oo][0] = fmaf(bv[oo], w4.x, acc2[oo][0]);
            acc2[oo][1] = fmaf(bv[oo], w4.y, acc2[oo][1]);
            acc2[oo][2] = fmaf(bv[oo], w4.z, acc2[oo][2]);
            acc2[oo][3] = fmaf(bv[oo], w4.w, acc2[oo][3]);
        }
    }
    float w_[16];
#pragma unroll
    for (int oo = 0; oo < 16; ++oo) {
#pragma unroll
        for (int jj = 0; jj < 4; ++jj) {
            acc2[oo][jj] += __shfl_xor(acc2[oo][jj], 1);
            acc2[oo][jj] += __shfl_xor(acc2[oo][jj], 2);
        }
        float v01 = (kp & 1) ? acc2[oo][1] : acc2[oo][0];
        float v23 = (kp & 1) ? acc2[oo][3] : acc2[oo][2];
        w_[oo] = (kp & 2) ? v23 : v01;   // l == tid
    }
    float bb2 = ba2[tid];
#pragma unroll
    for (int oo = 0; oo < 16; ++oo) w_[oo] += bb2;

    // softmax over l per oo, then weighted sum
    red16<true>(w_, sO, scr);
    float e_[16];
#pragma unroll
    for (int oo = 0; oo < 16; ++oo) e_[oo] = __expf(w_[oo] - sO[oo]);
    red16<false>(e_, sS, scr);
#pragma unroll
    for (int oo = 0; oo < 16; ++oo) tmp[oo] = vv[oo] * e_[oo] / sS[oo];
    red16<false>(tmp, sQ, scr);
    if (tid < 16) out[bs * 128 + o0 + tid] = sQ[tid];
}

// ---------------------------------------------------------------------------
// Launch
// ---------------------------------------------------------------------------
extern "C" void kernel_launch(void* const* d_in, const int* in_sizes, int n_in,
                              void* d_out, int out_size, void* d_ws, size_t ws_size,
                              hipStream_t stream) {
    const float* x      = (const float*)d_in[0];
    const float* ln0_g  = (const float*)d_in[1];
    const float* ln0_b  = (const float*)d_in[2];
    const float* W0     = (const float*)d_in[3];
    const float* b0     = (const float*)d_in[4];
    const float* rln_g  = (const float*)d_in[5];
    const float* rln_b  = (const float*)d_in[6];
    const float* rW     = (const float*)d_in[7];
    const float* rb     = (const float*)d_in[8];
    const float* lnf_g  = (const float*)d_in[9];
    const float* lnf_b  = (const float*)d_in[10];
    const float* Wf     = (const float*)d_in[11];
    const float* bf_    = (const float*)d_in[12];
    const float* ln1_g  = (const float*)d_in[13];
    const float* ln1_b  = (const float*)d_in[14];
    const float* Wa1    = (const float*)d_in[15];
    const float* ba1    = (const float*)d_in[16];
    const float* ln2_g  = (const float*)d_in[17];
    const float* ln2_b  = (const float*)d_in[18];
    const float* Wa2    = (const float*)d_in[19];
    const float* ba2    = (const float*)d_in[20];
    float* out = (float*)d_out;

    const int R = 64 * 256;   // 16384 rows
    float*  h  = (float*)d_ws;                          // R*1024 f32   (64 MB)
    ushort* Ap = (ushort*)(h + (size_t)R * 1024);       // R*1024*2 u16 (64 MB)
    float*  fc = (float*)(Ap + (size_t)R * 2048);       // R*128 f32    (8 MB)
    ushort* Wp = (ushort*)(fc + (size_t)R * 128);       // up to 4 MB

    // stem: h = relu(LN(x) @ W0 + b0)
    conv_w<<<dim3(16, 16), 64, 0, stream>>>(W0, Wp, 512, 1024);
    ln_pack<<<R, 256, 0, stream>>>(x, ln0_g, ln0_b, Ap, 512);
    gemm_mfma256<0><<<dim3(64, 4), 512, 0, stream>>>(Ap, Wp, b0, h, R, 1024, 512);

    // residual blocks
    for (int i = 0; i < 8; ++i) {
        conv_w<<<dim3(16, 32), 64, 0, stream>>>(rW + (size_t)i * 1024 * 1024, Wp, 1024, 1024);
        ln_pack<<<R, 256, 0, stream>>>(h, rln_g + i * 1024, rln_b + i * 1024, Ap, 1024);
        gemm_mfma256<1><<<dim3(64, 4), 512, 0, stream>>>(Ap, Wp, rb + i * 1024, h, R, 1024, 1024);
    }

    // head: fc = LN(h) @ Wf + bf  (N=128 -> 128^2 kernel)
    conv_w<<<dim3(2, 32), 64, 0, stream>>>(Wf, Wp, 1024, 128);
    ln_pack<<<R, 256, 0, stream>>>(h, lnf_g, lnf_b, Ap, 1024);
    gemm_mfma<2><<<dim3(128, 1), 256, 0, stream>>>(Ap, Wp, bf_, fc, R, 128, 1024);

    // fused attention + weighted sum (16 outputs per block)
    attn_g16<<<64 * 8, 256, 0, stream>>>(fc, ln1_g, ln1_b, Wa1, ba1,
                                         ln2_g, ln2_b, Wa2, ba2, out);
}

// Round 7
// 1235.426 us; speedup vs baseline: 1.0689x; 1.0689x over previous
//
#include <hip/hip_runtime.h>
#include <hip/hip_bf16.h>
#include <stdint.h>

#define EPSV 1e-5f

typedef __bf16 bf16x8 __attribute__((ext_vector_type(8)));
typedef float f32x4 __attribute__((ext_vector_type(4)));

// ---------------------------------------------------------------------------
// round-to-nearest bf16 split: f = hi + lo (both bf16), |f-(hi+lo)| ~ 2^-18 |f|
// ---------------------------------------------------------------------------
__device__ __forceinline__ void bf16split(float f, ushort& h, ushort& l) {
    union { float f; uint32_t u; } a; a.f = f;
    uint32_t r = a.u + 0x7FFFu + ((a.u >> 16) & 1u);
    h = (ushort)(r >> 16);
    union { uint32_t u; float f; } hf; hf.u = ((uint32_t)h) << 16;
    float lof = f - hf.f;
    union { float f; uint32_t u; } b; b.f = lof;
    uint32_t r2 = b.u + 0x7FFFu + ((b.u >> 16) & 1u);
    l = (ushort)(r2 >> 16);
}

__device__ __forceinline__ void gload_lds16(const void* g, void* l) {
    __builtin_amdgcn_global_load_lds(
        (const __attribute__((address_space(1))) uint32_t*)g,
        (__attribute__((address_space(3))) uint32_t*)l, 16, 0, 0);
}

// ---------------------------------------------------------------------------
// Block reduction helpers (256 threads = 4 waves of 64)
// ---------------------------------------------------------------------------
__device__ __forceinline__ float block_sum256(float v, float* red) {
#pragma unroll
    for (int off = 32; off; off >>= 1) v += __shfl_down(v, off);
    int lane = threadIdx.x & 63, w = threadIdx.x >> 6;
    __syncthreads();
    if (lane == 0) red[w] = v;
    __syncthreads();
    return red[0] + red[1] + red[2] + red[3];
}

// ---------------------------------------------------------------------------
// Row LayerNorm -> packed hi/lo bf16 output.
// Packed layout: Ap[row][kt][half][km]  (ushort), kt = k/32, km = k%32,
// half 0 = hi, 1 = lo. Row stride = D*2 ushorts = D*4 bytes.
// ---------------------------------------------------------------------------
__global__ __launch_bounds__(256)
void ln_pack(const float* __restrict__ X, const float* __restrict__ g,
             const float* __restrict__ b, ushort* __restrict__ Ap, int D) {
    __shared__ float red[4];
    int row = blockIdx.x;
    const float* x = X + (size_t)row * D;
    ushort* ap = Ap + (size_t)row * (D * 2);
    int tid = threadIdx.x;
    int nvec = D >> 2;

    float s = 0.f, sq = 0.f;
    for (int i = tid; i < nvec; i += 256) {
        float4 v = ((const float4*)x)[i];
        s += v.x + v.y + v.z + v.w;
        sq += v.x * v.x + v.y * v.y + v.z * v.z + v.w * v.w;
    }
    float ts = block_sum256(s, red);
    float tq = block_sum256(sq, red);
    float invD = 1.f / (float)D;
    float mu = ts * invD;
    float var = tq * invD - mu * mu;
    float rstd = rsqrtf(var + EPSV);

    for (int i = tid; i < nvec; i += 256) {
        float4 v = ((const float4*)x)[i];
        float4 gv = ((const float4*)g)[i];
        float4 bv = ((const float4*)b)[i];
        float o[4];
        o[0] = (v.x - mu) * rstd * gv.x + bv.x;
        o[1] = (v.y - mu) * rstd * gv.y + bv.y;
        o[2] = (v.z - mu) * rstd * gv.z + bv.z;
        o[3] = (v.w - mu) * rstd * gv.w + bv.w;
        ushort hi[4], lo[4];
#pragma unroll
        for (int j = 0; j < 4; ++j) bf16split(o[j], hi[j], lo[j]);
        int kt = i >> 3;           // (4i)/32
        int km = (i & 7) << 2;     // (4i)%32
        ushort* dst = ap + kt * 64 + km;
        *(ushort4*)dst = *(ushort4*)hi;
        *(ushort4*)(dst + 32) = *(ushort4*)lo;
    }
}

// ---------------------------------------------------------------------------
// Weight convert+transpose: W[K][N] fp32 -> Wp[n][kt][half][km] packed bf16.
// grid = (ceil(N/64), K/32), block = 64.
// ---------------------------------------------------------------------------
__global__ __launch_bounds__(64)
void conv_w(const float* __restrict__ W, ushort* __restrict__ Wp, int K, int N) {
    int n = blockIdx.x * 64 + threadIdx.x;
    int kt = blockIdx.y;
    if (n >= N) return;
    ushort hi[32], lo[32];
#pragma unroll
    for (int j = 0; j < 32; ++j) {
        float f = W[(size_t)(kt * 32 + j) * N + n];
        bf16split(f, hi[j], lo[j]);
    }
    ushort* dst = Wp + (size_t)n * (K * 2) + kt * 64;
    uint4* d = (uint4*)dst;
    const uint4* ph = (const uint4*)hi;
    const uint4* pl = (const uint4*)lo;
    d[0] = ph[0]; d[1] = ph[1]; d[2] = ph[2]; d[3] = ph[3];
    d[4] = pl[0]; d[5] = pl[1]; d[6] = pl[2]; d[7] = pl[3];
}

// ---------------------------------------------------------------------------
// 256x256-tile split-bf16 MFMA GEMM, 8 waves, double-buffered LDS,
// issue-early staging, ONE barrier per K-tile (round-5 proven; no setprio).
// ---------------------------------------------------------------------------
template <int MODE>
__global__ __launch_bounds__(512, 2)
void gemm_mfma256(const ushort* __restrict__ Ap, const ushort* __restrict__ Bp,
                  const float* __restrict__ bias, float* __restrict__ C,
                  int M, int N, int K) {
    __shared__ ushort Abuf[2][256 * 64];   // 2 x 32 KB
    __shared__ ushort Bbuf[2][256 * 64];   // 2 x 32 KB

    const int tid = threadIdx.x;
    const int lane = tid & 63;
    const int wv = tid >> 6;       // 0..7
    const int wr = wv >> 2;        // 0..1  (M)
    const int wc = wv & 3;         // 0..3  (N)

    // T1 XCD-chunked swizzle
    int lid = blockIdx.y * gridDim.x + blockIdx.x;
    int nwg = gridDim.x * gridDim.y;
    int chunk = nwg >> 3;
    int swz = (lid & 7) * chunk + (lid >> 3);
    int nIdx = swz % gridDim.y;
    int mIdx = swz / gridDim.y;
    const int m0 = mIdx * 256, n0 = nIdx * 256;

    const int nt = K >> 5;
    const size_t rowB = (size_t)K * 4;   // packed row bytes

    int srow[4], sq[4];
#pragma unroll
    for (int i = 0; i < 4; ++i) {
        int s = i * 512 + tid;
        srow[i] = s >> 3;                  // 0..255
        sq[i] = (s & 7) ^ (srow[i] & 7);
    }

    f32x4 acc[8][4] = {};

    // prologue: stage tile 0 into buffer 0
#pragma unroll
    for (int i = 0; i < 4; ++i) {
        const char* sA = (const char*)Ap + (size_t)(m0 + srow[i]) * rowB + sq[i] * 16;
        const char* sB = (const char*)Bp + (size_t)(n0 + srow[i]) * rowB + sq[i] * 16;
        gload_lds16(sA, (char*)Abuf[0] + (i * 512 + tid) * 16);
        gload_lds16(sB, (char*)Bbuf[0] + (i * 512 + tid) * 16);
    }
    __syncthreads();

    int p = 0;
    for (int kt = 0; kt < nt; ++kt) {
        if (kt + 1 < nt) {
            const size_t koff = (size_t)(kt + 1) * 128;
#pragma unroll
            for (int i = 0; i < 4; ++i) {
                const char* sA = (const char*)Ap + (size_t)(m0 + srow[i]) * rowB + koff + sq[i] * 16;
                const char* sB = (const char*)Bp + (size_t)(n0 + srow[i]) * rowB + koff + sq[i] * 16;
                gload_lds16(sA, (char*)Abuf[p ^ 1] + (i * 512 + tid) * 16);
                gload_lds16(sB, (char*)Bbuf[p ^ 1] + (i * 512 + tid) * 16);
            }
        }

        const char* Ab = (const char*)Abuf[p];
        const char* Bb = (const char*)Bbuf[p];
        const int g = lane >> 4;
        const int rr = lane & 15;

        // P1: hi(A) x hi(B)
        bf16x8 ah[8], bh[4];
#pragma unroll
        for (int m = 0; m < 8; ++m) {
            int rA = wr * 128 + m * 16 + rr;
            ah[m] = *(const bf16x8*)(Ab + rA * 128 + ((g ^ (rA & 7)) * 16));
        }
#pragma unroll
        for (int n = 0; n < 4; ++n) {
            int rB = wc * 64 + n * 16 + rr;
            bh[n] = *(const bf16x8*)(Bb + rB * 128 + ((g ^ (rB & 7)) * 16));
        }
#pragma unroll
        for (int m = 0; m < 8; ++m)
#pragma unroll
            for (int n = 0; n < 4; ++n)
                acc[m][n] = __builtin_amdgcn_mfma_f32_16x16x32_bf16(ah[m], bh[n], acc[m][n], 0, 0, 0);

        // P2: lo(A) x hi(B)
        {
            bf16x8 al[8];
#pragma unroll
            for (int m = 0; m < 8; ++m) {
                int rA = wr * 128 + m * 16 + rr;
                al[m] = *(const bf16x8*)(Ab + rA * 128 + (((g + 4) ^ (rA & 7)) * 16));
            }
#pragma unroll
            for (int m = 0; m < 8; ++m)
#pragma unroll
                for (int n = 0; n < 4; ++n)
                    acc[m][n] = __builtin_amdgcn_mfma_f32_16x16x32_bf16(al[m], bh[n], acc[m][n], 0, 0, 0);
        }
        // P3: hi(A) x lo(B)
        {
            bf16x8 bl[4];
#pragma unroll
            for (int n = 0; n < 4; ++n) {
                int rB = wc * 64 + n * 16 + rr;
                bl[n] = *(const bf16x8*)(Bb + rB * 128 + (((g + 4) ^ (rB & 7)) * 16));
            }
#pragma unroll
            for (int m = 0; m < 8; ++m)
#pragma unroll
                for (int n = 0; n < 4; ++n)
                    acc[m][n] = __builtin_amdgcn_mfma_f32_16x16x32_bf16(ah[m], bl[n], acc[m][n], 0, 0, 0);
        }

        __syncthreads();
        p ^= 1;
    }

    // epilogue: C/D layout col = lane&15, row = (lane>>4)*4 + j  [m89/m91]
#pragma unroll
    for (int m = 0; m < 8; ++m) {
        int r = m0 + wr * 128 + m * 16 + (lane >> 4) * 4;
#pragma unroll
        for (int n = 0; n < 4; ++n) {
            int c = n0 + wc * 64 + n * 16 + (lane & 15);
            float bv = bias[c];
#pragma unroll
            for (int j = 0; j < 4; ++j) {
                float v = acc[m][n][j] + bv;
                float* cp = &C[(size_t)(r + j) * N + c];
                if (MODE == 0) *cp = fmaxf(v, 0.f);
                else if (MODE == 1) *cp = *cp + fmaxf(v, 0.f);
                else *cp = v;
            }
        }
    }
}

// ---------------------------------------------------------------------------
// 128x128-tile split-bf16 MFMA GEMM (proven) -- head (N=128).
// ---------------------------------------------------------------------------
template <int MODE>
__global__ __launch_bounds__(256)
void gemm_mfma(const ushort* __restrict__ Ap, const ushort* __restrict__ Bp,
               const float* __restrict__ bias, float* __restrict__ C,
               int M, int N, int K) {
    __shared__ ushort Ash[128 * 64];
    __shared__ ushort Bsh[128 * 64];

    const int tid = threadIdx.x;
    const int lane = tid & 63;
    const int wv = tid >> 6;
    const int wr = wv >> 1, wc = wv & 1;

    int lid = blockIdx.y * gridDim.x + blockIdx.x;
    int nwg = gridDim.x * gridDim.y;
    int chunk = nwg >> 3;
    int swz = (lid & 7) * chunk + (lid >> 3);
    int nIdx = swz % gridDim.y;
    int mIdx = swz / gridDim.y;
    const int m0 = mIdx * 128, n0 = nIdx * 128;

    const int ktc = K >> 5;
    const size_t rowB = (size_t)K * 4;

    int srow[4], sq[4];
#pragma unroll
    for (int i = 0; i < 4; ++i) {
        int s = i * 256 + tid;
        srow[i] = s >> 3;
        sq[i] = (s & 7) ^ (srow[i] & 7);
    }

    f32x4 acc[4][4] = {};

    for (int kt = 0; kt < ktc; ++kt) {
        __syncthreads();
#pragma unroll
        for (int i = 0; i < 4; ++i) {
            const char* sA = (const char*)Ap + (size_t)(m0 + srow[i]) * rowB + kt * 128 + sq[i] * 16;
            const char* sB = (const char*)Bp + (size_t)(n0 + srow[i]) * rowB + kt * 128 + sq[i] * 16;
            gload_lds16(sA, (char*)Ash + (i * 256 + tid) * 16);
            gload_lds16(sB, (char*)Bsh + (i * 256 + tid) * 16);
        }
        __syncthreads();

        bf16x8 ah[4], al[4], bh[4], bl[4];
        const int g = lane >> 4;
        const int rr = lane & 15;
#pragma unroll
        for (int t = 0; t < 4; ++t) {
            int rA = wr * 64 + t * 16 + rr;
            const char* baseA = (const char*)Ash + rA * 128;
            ah[t] = *(const bf16x8*)(baseA + ((g ^ (rA & 7)) * 16));
            al[t] = *(const bf16x8*)(baseA + (((g + 4) ^ (rA & 7)) * 16));
            int rBr = wc * 64 + t * 16 + rr;
            const char* baseB = (const char*)Bsh + rBr * 128;
            bh[t] = *(const bf16x8*)(baseB + ((g ^ (rBr & 7)) * 16));
            bl[t] = *(const bf16x8*)(baseB + (((g + 4) ^ (rBr & 7)) * 16));
        }
#pragma unroll
        for (int mi = 0; mi < 4; ++mi)
#pragma unroll
            for (int ni = 0; ni < 4; ++ni) {
                acc[mi][ni] = __builtin_amdgcn_mfma_f32_16x16x32_bf16(ah[mi], bh[ni], acc[mi][ni], 0, 0, 0);
                acc[mi][ni] = __builtin_amdgcn_mfma_f32_16x16x32_bf16(al[mi], bh[ni], acc[mi][ni], 0, 0, 0);
                acc[mi][ni] = __builtin_amdgcn_mfma_f32_16x16x32_bf16(ah[mi], bl[ni], acc[mi][ni], 0, 0, 0);
            }
    }

#pragma unroll
    for (int mi = 0; mi < 4; ++mi) {
        int r = m0 + wr * 64 + mi * 16 + (lane >> 4) * 4;
#pragma unroll
        for (int ni = 0; ni < 4; ++ni) {
            int c = n0 + wc * 64 + ni * 16 + (lane & 15);
            float bv = bias[c];
#pragma unroll
            for (int j = 0; j < 4; ++j) {
                float v = acc[mi][ni][j] + bv;
                float* cp = &C[(size_t)(r + j) * N + c];
                if (MODE == 0) *cp = fmaxf(v, 0.f);
                else if (MODE == 1) *cp = *cp + fmaxf(v, 0.f);
                else *cp = v;
            }
        }
    }
}

// ---------------------------------------------------------------------------
// 16-wide simultaneous block reduction: v[16] per thread -> out[16] (shared).
// ---------------------------------------------------------------------------
template <bool MAXOP>
__device__ __forceinline__ void red16(const float* v, float* out, float (*scr)[4]) {
    int lane = threadIdx.x & 63, wv = threadIdx.x >> 6, tid = threadIdx.x;
#pragma unroll
    for (int oo = 0; oo < 16; ++oo) {
        float r = v[oo];
#pragma unroll
        for (int m = 1; m < 64; m <<= 1) {
            float t = __shfl_xor(r, m);
            r = MAXOP ? fmaxf(r, t) : r + t;
        }
        if (lane == 0) scr[oo][wv] = r;
    }
    __syncthreads();
    if (tid < 16) {
        float a = scr[tid][0], b = scr[tid][1], c = scr[tid][2], d = scr[tid][3];
        out[tid] = MAXOP ? fmaxf(fmaxf(a, b), fmaxf(c, d)) : (a + b + c + d);
    }
    __syncthreads();
}

// ---------------------------------------------------------------------------
// Attention over time, 16 outputs per block. grid = 64 bs * 8 ogroups.
// GEMV phases use P=2 j-blocking: thread (jgrp = tid>>1, kp = tid&1) owns
// 2 output columns j = jgrp*2+{0,1}, iterating k = 2*i+kp. Partials reduced
// over kp with 1 shfl_xor; thread keeps column jj==kp so j == tid (all
// LN/softmax phases unchanged). acc[16][2]=32 regs -> no spill (round-6
// post-mortem: P=4 needed 64+ acc regs and spilled everything to scratch).
// buf rows padded to 20 floats: the 2 kp-lane addresses differ by 80B ->
// each b128 has only 2 distinct addresses (2-way = free broadcast).
// ---------------------------------------------------------------------------
__global__ __launch_bounds__(256)
void attn_g16(const float* __restrict__ fc,
              const float* __restrict__ g1, const float* __restrict__ b1,
              const float* __restrict__ Wa1, const float* __restrict__ ba1,
              const float* __restrict__ g2, const float* __restrict__ b2,
              const float* __restrict__ Wa2, const float* __restrict__ ba2,
              float* __restrict__ out) {
    __shared__ float buf[257][20];
    __shared__ float scr[16][4];
    __shared__ float sS[16], sQ[16], sO[16];

    int bs = blockIdx.x >> 3;
    int o0 = (blockIdx.x & 7) * 16;
    int tid = threadIdx.x;
    int jgrp = tid >> 1;
    int kp = tid & 1;

    float vv[16], tmp[16];
    const float4* fp = (const float4*)(fc + (size_t)(bs * 256 + tid) * 128 + o0);
#pragma unroll
    for (int q = 0; q < 4; ++q) {
        float4 t = fp[q];
        vv[4 * q] = t.x; vv[4 * q + 1] = t.y; vv[4 * q + 2] = t.z; vv[4 * q + 3] = t.w;
    }

#pragma unroll
    for (int oo = 0; oo < 16; ++oo) tmp[oo] = vv[oo] * vv[oo];
    red16<false>(vv, sS, scr);
    red16<false>(tmp, sQ, scr);

    // LN over 257-vector [v_0..255, mean]; buf[l][oo] = normalized t
    float gl = g1[tid], bl = b1[tid];
#pragma unroll
    for (int oo = 0; oo < 16; ++oo) {
        float s = sS[oo], q = sQ[oo];
        float mean = s * (1.f / 256.f);
        float mu = (s + mean) * (1.f / 257.f);
        float var = (q + mean * mean) * (1.f / 257.f) - mu * mu;
        float rstd = rsqrtf(var + EPSV);
        tmp[oo] = (vv[oo] - mu) * rstd * gl + bl;
    }
#pragma unroll
    for (int q = 0; q < 4; ++q)
        *(float4*)&buf[tid][4 * q] = *(float4*)&tmp[4 * q];
    if (tid < 16) {
        int oo = tid;
        float s = sS[oo], q = sQ[oo];
        float mean = s * (1.f / 256.f);
        float mu = (s + mean) * (1.f / 257.f);
        float var = (q + mean * mean) * (1.f / 257.f) - mu * mu;
        float rstd = rsqrtf(var + EPSV);
        buf[256][oo] = (mean - mu) * rstd * g1[256] + b1[256];
    }
    __syncthreads();

    // GEMV1: acc1[oo][jj] = sum_{k ≡ kp (mod 2)} buf[k][oo] * Wa1[k][jgrp*2+jj]
    float acc1[16][2] = {};
#pragma unroll 2
    for (int i = 0; i < 128; ++i) {
        int k = 2 * i + kp;
        float2 wv2 = *(const float2*)&Wa1[(size_t)k * 256 + jgrp * 2];
        float4 t0 = *(const float4*)&buf[k][0];
        float4 t1 = *(const float4*)&buf[k][4];
        float4 t2 = *(const float4*)&buf[k][8];
        float4 t3 = *(const float4*)&buf[k][12];
        float bv[16] = { t0.x, t0.y, t0.z, t0.w, t1.x, t1.y, t1.z, t1.w,
                         t2.x, t2.y, t2.z, t2.w, t3.x, t3.y, t3.z, t3.w };
#pragma unroll
        for (int oo = 0; oo < 16; ++oo) {
            acc1[oo][0] = fmaf(bv[oo], wv2.x, acc1[oo][0]);
            acc1[oo][1] = fmaf(bv[oo], wv2.y, acc1[oo][1]);
        }
    }
    if (kp == 0) {   // k = 256 tail
        float2 wv2 = *(const float2*)&Wa1[(size_t)256 * 256 + jgrp * 2];
#pragma unroll
        for (int oo = 0; oo < 16; ++oo) {
            float bv = buf[256][oo];
            acc1[oo][0] = fmaf(bv, wv2.x, acc1[oo][0]);
            acc1[oo][1] = fmaf(bv, wv2.y, acc1[oo][1]);
        }
    }
    // reduce partials over kp (lane tid^1 shares jgrp); keep jj == kp -> j == tid
    float a_[16];
#pragma unroll
    for (int oo = 0; oo < 16; ++oo) {
        float p0 = acc1[oo][0] + __shfl_xor(acc1[oo][0], 1);
        float p1 = acc1[oo][1] + __shfl_xor(acc1[oo][1], 1);
        a_[oo] = kp ? p1 : p0;
    }
    float bb = ba1[tid];
#pragma unroll
    for (int oo = 0; oo < 16; ++oo) a_[oo] = fmaxf(a_[oo] + bb, 0.f);

    // LN over a (256 j's)
#pragma unroll
    for (int oo = 0; oo < 16; ++oo) tmp[oo] = a_[oo] * a_[oo];
    red16<false>(a_, sS, scr);
    red16<false>(tmp, sQ, scr);

    float g2l = g2[tid], b2l = b2[tid];
#pragma unroll
    for (int oo = 0; oo < 16; ++oo) {
        float mu2 = sS[oo] * (1.f / 256.f);
        float rstd2 = rsqrtf(sQ[oo] * (1.f / 256.f) - mu2 * mu2 + EPSV);
        tmp[oo] = (a_[oo] - mu2) * rstd2 * g2l + b2l;
    }
#pragma unroll
    for (int q = 0; q < 4; ++q)
        *(float4*)&buf[tid][4 * q] = *(float4*)&tmp[4 * q];
    __syncthreads();

    // GEMV2: same P=2 decomposition over j (256), l == tid
    float acc2[16][2] = {};
#pragma unroll 2
    for (int i = 0; i < 128; ++i) {
        int k = 2 * i + kp;
        float2 wv2 = *(const float2*)&Wa2[(size_t)k * 256 + jgrp * 2];
        float4 t0 = *(const float4*)&buf[k][0];
        float4 t1 = *(const float4*)&buf[k][4];
        float4 t2 = *(const float4*)&buf[k][8];
        float4 t3 = *(const float4*)&buf[k][12];
        float bv[16] = { t0.x, t0.y, t0.z, t0.w, t1.x, t1.y, t1.z, t1.w,
                         t2.x, t2.y, t2.z, t2.w, t3.x, t3.y, t3.z, t3.w };
#pragma unroll
        for (int oo = 0; oo < 16; ++oo) {
            acc2[oo][0] = fmaf(bv[oo], wv2.x, acc2[oo][0]);
            acc2[oo][1] = fmaf(bv[oo], wv2.y, acc2[oo][1]);
        }
    }
    float w_[16];
#pragma unroll
    for (int oo = 0; oo < 16; ++oo) {
        float p0 = acc2[oo][0] + __shfl_xor(acc2[oo][0], 1);
        float p1 = acc2[oo][1] + __shfl_xor(acc2[oo][1], 1);
        w_[oo] = kp ? p1 : p0;   // l == tid
    }
    float bb2 = ba2[tid];
#pragma unroll
    for (int oo = 0; oo < 16; ++oo) w_[oo] += bb2;

    // softmax over l per oo, then weighted sum
    red16<true>(w_, sO, scr);
    float e_[16];
#pragma unroll
    for (int oo = 0; oo < 16; ++oo) e_[oo] = __expf(w_[oo] - sO[oo]);
    red16<false>(e_, sS, scr);
#pragma unroll
    for (int oo = 0; oo < 16; ++oo) tmp[oo] = vv[oo] * e_[oo] / sS[oo];
    red16<false>(tmp, sQ, scr);
    if (tid < 16) out[bs * 128 + o0 + tid] = sQ[tid];
}

// ---------------------------------------------------------------------------
// Launch
// ---------------------------------------------------------------------------
extern "C" void kernel_launch(void* const* d_in, const int* in_sizes, int n_in,
                              void* d_out, int out_size, void* d_ws, size_t ws_size,
                              hipStream_t stream) {
    const float* x      = (const float*)d_in[0];
    const float* ln0_g  = (const float*)d_in[1];
    const float* ln0_b  = (const float*)d_in[2];
    const float* W0     = (const float*)d_in[3];
    const float* b0     = (const float*)d_in[4];
    const float* rln_g  = (const float*)d_in[5];
    const float* rln_b  = (const float*)d_in[6];
    const float* rW     = (const float*)d_in[7];
    const float* rb     = (const float*)d_in[8];
    const float* lnf_g  = (const float*)d_in[9];
    const float* lnf_b  = (const float*)d_in[10];
    const float* Wf     = (const float*)d_in[11];
    const float* bf_    = (const float*)d_in[12];
    const float* ln1_g  = (const float*)d_in[13];
    const float* ln1_b  = (const float*)d_in[14];
    const float* Wa1    = (const float*)d_in[15];
    const float* ba1    = (const float*)d_in[16];
    const float* ln2_g  = (const float*)d_in[17];
    const float* ln2_b  = (const float*)d_in[18];
    const float* Wa2    = (const float*)d_in[19];
    const float* ba2    = (const float*)d_in[20];
    float* out = (float*)d_out;

    const int R = 64 * 256;   // 16384 rows
    float*  h  = (float*)d_ws;                          // R*1024 f32   (64 MB)
    ushort* Ap = (ushort*)(h + (size_t)R * 1024);       // R*1024*2 u16 (64 MB)
    float*  fc = (float*)(Ap + (size_t)R * 2048);       // R*128 f32    (8 MB)
    ushort* Wp = (ushort*)(fc + (size_t)R * 128);       // up to 4 MB

    // stem: h = relu(LN(x) @ W0 + b0)
    conv_w<<<dim3(16, 16), 64, 0, stream>>>(W0, Wp, 512, 1024);
    ln_pack<<<R, 256, 0, stream>>>(x, ln0_g, ln0_b, Ap, 512);
    gemm_mfma256<0><<<dim3(64, 4), 512, 0, stream>>>(Ap, Wp, b0, h, R, 1024, 512);

    // residual blocks
    for (int i = 0; i < 8; ++i) {
        conv_w<<<dim3(16, 32), 64, 0, stream>>>(rW + (size_t)i * 1024 * 1024, Wp, 1024, 1024);
        ln_pack<<<R, 256, 0, stream>>>(h, rln_g + i * 1024, rln_b + i * 1024, Ap, 1024);
        gemm_mfma256<1><<<dim3(64, 4), 512, 0, stream>>>(Ap, Wp, rb + i * 1024, h, R, 1024, 1024);
    }

    // head: fc = LN(h) @ Wf + bf  (N=128 -> 128^2 kernel)
    conv_w<<<dim3(2, 32), 64, 0, stream>>>(Wf, Wp, 1024, 128);
    ln_pack<<<R, 256, 0, stream>>>(h, lnf_g, lnf_b, Ap, 1024);
    gemm_mfma<2><<<dim3(128, 1), 256, 0, stream>>>(Ap, Wp, bf_, fc, R, 128, 1024);

    // fused attention + weighted sum (16 outputs per block)
    attn_g16<<<64 * 8, 256, 0, stream>>>(fc, ln1_g, ln1_b, Wa1, ba1,
                                         ln2_g, ln2_b, Wa2, ba2, out);
}